// Round 1
// 11895.711 us; speedup vs baseline: 2.5804x; 2.5804x over previous
//
#include <hip/hip_runtime.h>
#include <math.h>

// Problem constants
#define RNN_B 64
#define RNN_T 512
#define RNN_IN 512
#define RNN_H 1024

// ws layout (float offsets):
//   0       h0buf[0]   (H*B = 65536 floats, layout [n][b])
//   65536   h1buf[0]
//   131072  h0buf[1]   <- zeroed each launch (initial h0_{-1})
//   196608  h1buf[1]   <- zeroed each launch (initial h1_{-1})
//   262144  gen (u32, barrier generation)
//   262160  flags[256] (u32 per block)
// total needed: 262416 floats ~= 1.05 MB

__device__ __forceinline__ void fma16(float4 acc[4], const float4 w, const float4 h) {
  acc[0].x = fmaf(w.x, h.x, acc[0].x); acc[0].y = fmaf(w.x, h.y, acc[0].y);
  acc[0].z = fmaf(w.x, h.z, acc[0].z); acc[0].w = fmaf(w.x, h.w, acc[0].w);
  acc[1].x = fmaf(w.y, h.x, acc[1].x); acc[1].y = fmaf(w.y, h.y, acc[1].y);
  acc[1].z = fmaf(w.y, h.z, acc[1].z); acc[1].w = fmaf(w.y, h.w, acc[1].w);
  acc[2].x = fmaf(w.z, h.x, acc[2].x); acc[2].y = fmaf(w.z, h.y, acc[2].y);
  acc[2].z = fmaf(w.z, h.z, acc[2].z); acc[2].w = fmaf(w.z, h.w, acc[2].w);
  acc[3].x = fmaf(w.w, h.x, acc[3].x); acc[3].y = fmaf(w.w, h.y, acc[3].y);
  acc[3].z = fmaf(w.w, h.z, acc[3].z); acc[3].w = fmaf(w.w, h.w, acc[3].w);
}

// sum over the 4-way intra-wave k split (lane bits 4,5)
__device__ __forceinline__ void reduce_kq4(float4 acc[4]) {
  #pragma unroll
  for (int m = 16; m <= 32; m <<= 1) {
    #pragma unroll
    for (int c = 0; c < 4; ++c) {
      acc[c].x += __shfl_xor(acc[c].x, m, 64);
      acc[c].y += __shfl_xor(acc[c].y, m, 64);
      acc[c].z += __shfl_xor(acc[c].z, m, 64);
      acc[c].w += __shfl_xor(acc[c].w, m, 64);
    }
  }
}

// Barrier v2: flag-array arrive (release store, no RMW), block-0 wave-0 gather
// with RELAXED agent loads, generation publish, relaxed spin + ONE acquire
// fence on exit. Avoids 256-way same-line fetch_add serialization and the
// per-poll buffer_inv of an ACQUIRE spin. Cross-XCD visibility per G16:
// release(flag) -> gather-read -> acquire fence -> release(gen) -> spin-read
// -> acquire fence. Gather wave = one HW wave, so its fence covers its loads.
__device__ __forceinline__ void grid_barrier(unsigned* gen, unsigned* flags,
                                             unsigned target) {
  __syncthreads();  // all waves drain their stores (compiler emits vmcnt(0))
  const int tid = threadIdx.x;
  if (tid == 0) {
    __hip_atomic_store(flags + blockIdx.x, target, __ATOMIC_RELEASE,
                       __HIP_MEMORY_SCOPE_AGENT);
  }
  if (blockIdx.x == 0) {
    if (tid < 64) {  // wave 0 gathers all 256 flags (4 per lane)
      for (;;) {
        bool ok = true;
        #pragma unroll
        for (int i = 0; i < 4; ++i) {
          unsigned v = __hip_atomic_load(flags + tid + 64 * i, __ATOMIC_RELAXED,
                                         __HIP_MEMORY_SCOPE_AGENT);
          ok &= (v >= target);
        }
        if (__all(ok)) break;
        __builtin_amdgcn_s_sleep(2);
      }
      if (tid == 0) {
        __builtin_amdgcn_fence(__ATOMIC_ACQUIRE, "agent");
        __hip_atomic_store(gen, target, __ATOMIC_RELEASE,
                           __HIP_MEMORY_SCOPE_AGENT);
      }
    }
  } else {
    if (tid == 0) {
      while (__hip_atomic_load(gen, __ATOMIC_RELAXED,
                               __HIP_MEMORY_SCOPE_AGENT) < target) {
        __builtin_amdgcn_s_sleep(2);
      }
      __builtin_amdgcn_fence(__ATOMIC_ACQUIRE, "agent");  // one inv per phase
    }
  }
  __syncthreads();
}

// ---------------------------------------------------------------------------
// Precompute: pre[n][b](t) = x[b,t,:]·W_ih0[n,:] + b_ih0[n] + b_hh0[n]
// NEW layout: written into out at slot (b' = rnnbid>>2, t, (rnnbid&3)*256)
// as 256 contiguous floats ordered [nl][b] for rnn block rnnbid = n>>2.
// That slot is clobbered by the h1_t store at phase t+1 and read at phase t
// -> lifetime safe, and the rnn kernel's read is 16 coalesced lines instead
// of 256 scattered ones.
// ---------------------------------------------------------------------------
__global__ __launch_bounds__(256) void pre_kernel(
    const float* __restrict__ x, const float* __restrict__ Wih0,
    const float* __restrict__ bih0, const float* __restrict__ bhh0,
    float* __restrict__ out)
{
  __shared__ float xs[64][68];  // [k][b], +4 pad keeps float4 alignment
  __shared__ float wl[64][68];  // [k][n]
  const int t  = blockIdx.y;
  const int n0 = blockIdx.x * 64;
  const int tid = threadIdx.x;
  const int tx = tid & 15;   // b-quad
  const int ty = tid >> 4;   // n-quad
  const int kf4 = tid & 15;  // staging: k float4 index
  const int row = tid >> 4;  // staging: row group

  float4 acc[4];
  acc[0] = acc[1] = acc[2] = acc[3] = make_float4(0.f, 0.f, 0.f, 0.f);

  for (int k0 = 0; k0 < RNN_IN; k0 += 64) {
    #pragma unroll
    for (int r = 0; r < 4; ++r) {
      const int rr = row + 16 * r;
      float4 v = *(const float4*)(x + ((size_t)rr * RNN_T + t) * RNN_IN + k0 + kf4 * 4);
      xs[kf4*4+0][rr] = v.x; xs[kf4*4+1][rr] = v.y;
      xs[kf4*4+2][rr] = v.z; xs[kf4*4+3][rr] = v.w;
      float4 w = *(const float4*)(Wih0 + (size_t)(n0 + rr) * RNN_IN + k0 + kf4 * 4);
      wl[kf4*4+0][rr] = w.x; wl[kf4*4+1][rr] = w.y;
      wl[kf4*4+2][rr] = w.z; wl[kf4*4+3][rr] = w.w;
    }
    __syncthreads();
    #pragma unroll 8
    for (int k = 0; k < 64; ++k) {
      float4 xv = *(const float4*)&xs[k][tx * 4];
      float4 wv = *(const float4*)&wl[k][ty * 4];
      fma16(acc, wv, xv);
    }
    __syncthreads();
  }

  // add bias; stage as xs[n_local][b]
  #pragma unroll
  for (int i = 0; i < 4; ++i) {
    const int n = n0 + ty * 4 + i;
    const float bi = bih0[n] + bhh0[n];
    xs[ty*4+i][tx*4+0] = acc[i].x + bi;
    xs[ty*4+i][tx*4+1] = acc[i].y + bi;
    xs[ty*4+i][tx*4+2] = acc[i].z + bi;
    xs[ty*4+i][tx*4+3] = acc[i].w + bi;
  }
  __syncthreads();
  // write block-local slices: rnnbid = blockIdx.x*16 + (nloc>>2)
  // dst = ((rnnbid>>2)*T + t)*H + (rnnbid&3)*256 + (nloc&3)*64 + b
  #pragma unroll
  for (int rep = 0; rep < 4; ++rep) {
    const int idx = tid + 256 * rep;   // 0..1023
    const int nloc = idx >> 4;         // 0..63
    const int bq4 = idx & 15;          // b float4 index
    float4 o = *(const float4*)(&xs[nloc][bq4 * 4]);
    const size_t dst = ((size_t)(blockIdx.x * 4 + (nloc >> 4)) * RNN_T + t) * RNN_H
                     + (size_t)((nloc >> 2) & 3) * 256 + (nloc & 3) * 64 + bq4 * 4;
    *(float4*)(out + dst) = o;
  }
}

// ---------------------------------------------------------------------------
// Persistent recurrence kernel (cooperative, 256 blocks x 1024 threads).
// Block owns columns n0..n0+3 of both h0 and h1; weight rows live in LDS.
// Lane mapping: bq = lane&15 (b quad), kq4 = lane>>4; k = j*64 + wave*4 + kq4
// -> every wave global load is a contiguous 1 KB block (16 fully-used lines),
// vs the old 1KB-lane-stride pattern (32 half-used lines). Reduce = 2 shfl
// stages (kq4) + 16-way LDS reduce across waves. 16 waves/CU for latency
// hiding (was 8).
// ---------------------------------------------------------------------------
__global__ __launch_bounds__(1024, 1) void rnn_kernel(
    const float* __restrict__ Whh0, const float* __restrict__ Wih1,
    const float* __restrict__ Whh1, const float* __restrict__ bih1,
    const float* __restrict__ bhh1, float* __restrict__ out,
    float* __restrict__ hws)
{
  __shared__ float w0[RNN_H * 4];   // [k][4n] Whh0 rows, 16 KB
  __shared__ float w1[RNN_H * 8];   // [k][4n] Wih1 rows then Whh1 rows, 32 KB
  __shared__ float part[16 * 256];  // per-wave partials [w][nl*64+b], 16 KB
  __shared__ float tile[256];       // h1 transpose staging for out, 1 KB

  const int tid = threadIdx.x;
  const int bid = blockIdx.x;
  const int n0 = bid * 4;

  // stage this block's weight rows into LDS (once); thread tid = k
  {
    const float* s0 = Whh0 + (size_t)n0 * RNN_H;
    const float* s1 = Wih1 + (size_t)n0 * RNN_H;
    const float* s2 = Whh1 + (size_t)n0 * RNN_H;
    #pragma unroll
    for (int nl = 0; nl < 4; ++nl) {
      w0[tid * 4 + nl]        = s0[(size_t)nl * RNN_H + tid];
      w1[tid * 4 + nl]        = s1[(size_t)nl * RNN_H + tid];
      w1[4096 + tid * 4 + nl] = s2[(size_t)nl * RNN_H + tid];
    }
  }
  float mybias = 0.f;  // per-thread scalar (avoid runtime-indexed array, rule #20)
  if (tid < 256) mybias = bih1[n0 + (tid >> 6)] + bhh1[n0 + (tid >> 6)];
  __syncthreads();

  const int wav  = tid >> 6;        // 0..15
  const int lane = tid & 63;
  const int kq4  = lane >> 4;       // 0..3 intra-wave k split
  const int bq   = lane & 15;       // b quad
  const int coff  = (wav * 4 + kq4) * RNN_B + bq * 4;  // into h bufs [k][b]
  const int wcoff = (wav * 4 + kq4) * 4;               // into w LDS [k][4]

  unsigned* gen   = (unsigned*)(hws + 262144);
  unsigned* flags = (unsigned*)(hws + 262160);
  float* h0buf[2] = { hws,         hws + 131072 };
  float* h1buf[2] = { hws + 65536, hws + 196608 };

  // x-contribution for phase 0, prefetched into a register
  float preval = 0.f;
  if (tid < 256)
    preval = out[(size_t)(bid >> 2) * RNN_T * RNN_H + (size_t)(bid & 3) * 256 + tid];

  for (int p = 0; p <= RNN_T; ++p) {
    // ---- layer 0: h0_p = tanh(pre[:,p,:] + h0_{p-1} @ Whh0^T) ----
    if (p < RNN_T) {
      const float* hp = h0buf[(p + 1) & 1];
      float4 acc[4];
      acc[0] = acc[1] = acc[2] = acc[3] = make_float4(0.f, 0.f, 0.f, 0.f);
      #pragma unroll
      for (int j = 0; j < 16; ++j) {            // k = j*64 + wav*4 + kq4
        float4 hv = *(const float4*)(hp + coff + j * 4096);
        float4 wv = *(const float4*)(w0 + wcoff + j * 256);
        fma16(acc, wv, hv);
      }
      reduce_kq4(acc);
      if (lane < 16) {                          // bq == lane
        #pragma unroll
        for (int nl = 0; nl < 4; ++nl)
          *(float4*)(part + wav * 256 + nl * 64 + lane * 4) = acc[nl];
      }
      __syncthreads();
      if (tid < 256) {                          // tid = nl*64 + b
        float s = preval;
        #pragma unroll
        for (int w = 0; w < 16; ++w) s += part[w * 256 + tid];
        h0buf[p & 1][n0 * RNN_B + tid] = tanhf(s);
      }
      __syncthreads();  // guard part reuse by layer 1
    }
    // ---- layer 1: h1_t = tanh(h0_t @ Wih1^T + h1_{t-1} @ Whh1^T + b), t=p-1 ----
    if (p >= 1) {
      const int t = p - 1;
      const float* h0t = h0buf[t & 1];
      const float* h1p = h1buf[(t + 1) & 1];
      float4 acc[4];
      acc[0] = acc[1] = acc[2] = acc[3] = make_float4(0.f, 0.f, 0.f, 0.f);
      #pragma unroll
      for (int j = 0; j < 16; ++j) {
        float4 hv = *(const float4*)(h0t + coff + j * 4096);
        float4 wv = *(const float4*)(w1 + wcoff + j * 256);
        fma16(acc, wv, hv);
      }
      #pragma unroll
      for (int j = 0; j < 16; ++j) {
        float4 hv = *(const float4*)(h1p + coff + j * 4096);
        float4 wv = *(const float4*)(w1 + 4096 + wcoff + j * 256);
        fma16(acc, wv, hv);
      }
      reduce_kq4(acc);
      if (lane < 16) {
        #pragma unroll
        for (int nl = 0; nl < 4; ++nl)
          *(float4*)(part + wav * 256 + nl * 64 + lane * 4) = acc[nl];
      }
      __syncthreads();
      if (tid < 256) {
        float s = mybias;
        #pragma unroll
        for (int w = 0; w < 16; ++w) s += part[w * 256 + tid];
        float v = tanhf(s);
        h1buf[t & 1][n0 * RNN_B + tid] = v;
        tile[tid] = v;
      }
      __syncthreads();
      if (tid < RNN_B) {  // out[b][t][n0..n0+3] as one float4 per b
        float4 o;
        o.x = tile[tid]; o.y = tile[64 + tid];
        o.z = tile[128 + tid]; o.w = tile[192 + tid];
        *(float4*)(out + ((size_t)tid * RNN_T + t) * RNN_H + n0) = o;
      }
    }
    // prefetch next phase's x-contribution BEFORE the barrier: the slot
    // (bid, p+1) is only clobbered by h1_{p+1} at phase p+2; the register
    // survives the barrier's cache invalidate, hiding the load entirely.
    if (tid < 256 && p + 1 < RNN_T)
      preval = out[((size_t)(bid >> 2) * RNN_T + (p + 1)) * RNN_H
                   + (size_t)(bid & 3) * 256 + tid];
    grid_barrier(gen, flags, (unsigned)(p + 1));
  }

  // h_final tail: out[BTH + l*B*H + b*H + n] ; finals live in buf index 1
  if (tid < 512) {
    const int l  = tid >> 8;        // 0..1
    const int b  = (tid >> 2) & 63;
    const int nl = tid & 3;
    const float* hf = (l == 0) ? (hws + 131072) : (hws + 196608);
    out[(size_t)RNN_B * RNN_T * RNN_H + ((size_t)l * RNN_B + b) * RNN_H + n0 + nl]
        = hf[(size_t)(n0 + nl) * RNN_B + b];
  }
}

extern "C" void kernel_launch(void* const* d_in, const int* in_sizes, int n_in,
                              void* d_out, int out_size, void* d_ws, size_t ws_size,
                              hipStream_t stream) {
  (void)in_sizes; (void)n_in; (void)out_size; (void)ws_size;
  const float* x    = (const float*)d_in[0];
  const float* Wih0 = (const float*)d_in[1];
  const float* Whh0 = (const float*)d_in[2];
  const float* bih0 = (const float*)d_in[3];
  const float* bhh0 = (const float*)d_in[4];
  const float* Wih1 = (const float*)d_in[5];
  const float* Whh1 = (const float*)d_in[6];
  const float* bih1 = (const float*)d_in[7];
  const float* bhh1 = (const float*)d_in[8];
  float* out = (float*)d_out;
  float* hws = (float*)d_ws;

  // zero initial h buffers (index 1) + gen + flags (ws is 0xAA-poisoned)
  hipMemsetAsync(hws + 131072, 0, (131072 + 272) * sizeof(float), stream);

  dim3 pg(16, 512);
  pre_kernel<<<pg, 256, 0, stream>>>(x, Wih0, bih0, bhh0, out);

  void* args[] = { (void*)&Whh0, (void*)&Wih1, (void*)&Whh1,
                   (void*)&bih1, (void*)&bhh1, (void*)&out, (void*)&hws };
  hipLaunchCooperativeKernel((const void*)rnn_kernel, dim3(256), dim3(1024),
                             args, 0, stream);
}